// Round 2
// baseline (181.910 us; speedup 1.0000x reference)
//
#include <hip/hip_runtime.h>
#include <hip/hip_bf16.h>

// Problem constants (fixed): n=4, b=8192, a=32, c_in=32, d_out=32,
// n_basis=36 (4 radii x 9 SH), ck=1152.
// inputs: [0] input (4,32,8192) f32, [1] coords (4,8192,3) f32,
//         [2] relative_mask (4,8192,32) f32, [3] W (32,32,36) f32,
//         [4] neighbors (4,8192,32) i32
// output: (4,32,8192) f32

typedef short bf16x8 __attribute__((ext_vector_type(8)));
typedef float f32x4  __attribute__((ext_vector_type(4)));

__device__ __forceinline__ unsigned int pack_bf16(float a, float b) {
    __hip_bfloat16 ha = __float2bfloat16(a);
    __hip_bfloat16 hb = __float2bfloat16(b);
    unsigned short ua = *reinterpret_cast<unsigned short*>(&ha);
    unsigned short ub = *reinterpret_cast<unsigned short*>(&hb);
    return ((unsigned int)ub << 16) | (unsigned int)ua;
}

// ---------------- prep: LDS-tiled transpose + W -> MFMA-A-fragment bf16 pack --------------
// Wfrag element t = ((kt*2+dt)*64 + l)*8 + j  holds  W[dt*16 + (l&15)][kt*32 + (l>>4)*8 + j]
__global__ __launch_bounds__(256) void prep_kernel(
    const float* __restrict__ inp, const float* __restrict__ W,
    float* __restrict__ inp_t, unsigned short* __restrict__ Wfrag)
{
    if (blockIdx.x < 1024) {
        // 32x32 tile transpose: (n,c,b) -> (n,b,c), coalesced both sides
        __shared__ float T[32][33];
        const int n  = blockIdx.x >> 8;          // 256 tiles per n
        const int b0 = (blockIdx.x & 255) << 5;
        const int bx = threadIdx.x & 31;
        const int cy = threadIdx.x >> 5;         // 0..7
        #pragma unroll
        for (int r = 0; r < 4; ++r) {
            const int cc = cy + r * 8;
            T[bx][cc] = inp[((n << 5) + cc) * 8192 + b0 + bx];
        }
        __syncthreads();
        #pragma unroll
        for (int r = 0; r < 4; ++r) {
            const int by = cy + r * 8;
            inp_t[((n << 13) + b0 + by) * 32 + bx] = T[by][bx];
        }
    } else {
        const int t = (blockIdx.x - 1024) * 256 + threadIdx.x;   // 0..36863
        if (t < 36 * 2 * 64 * 8) {
            const int j  = t & 7;
            const int l  = (t >> 3) & 63;
            const int dt = (t >> 9) & 1;
            const int kt = t >> 10;
            const int d  = dt * 16 + (l & 15);
            const int ck = kt * 32 + ((l >> 4) << 3) + j;
            __hip_bfloat16 h = __float2bfloat16(W[d * 1152 + ck]);
            Wfrag[t] = *reinterpret_cast<unsigned short*>(&h);
        }
    }
}

// ---------------- main fused kernel: 16 points/block ----------------
__global__ __launch_bounds__(256) void se3_main(
    const float* __restrict__ inp_t, const float* __restrict__ coords,
    const float* __restrict__ rmask, const int* __restrict__ neigh,
    const unsigned short* __restrict__ Wfrag, float* __restrict__ out)
{
    // per-wave geometry staging (broadcast-read in the a-loop)
    __shared__ __align__(16) float geomY[4][32][8];       // Y0..Y7          4096 B
    __shared__ __align__(16) float geomR[4][32][2][4];    // (rb2kh,rb2kh+1,Y8,0) 4096 B
    __shared__ int idxs[4][32];                           //                  512 B
    // M in bf16, MFMA-B layout: Mb[kt][p][kin], ck = kt*32+kin
    __shared__ __align__(16) unsigned short Mb[36 * 16 * 32];  //          36864 B
    __shared__ __align__(16) float Cp[4 * 64 * 4];        // partial C      4096 B

    const int tid  = threadIdx.x;
    const int lane = tid & 63;
    const int w    = tid >> 6;       // wave 0..3
    const int c    = lane & 31;
    const int kh   = lane >> 5;      // shells {2kh, 2kh+1}

    const int gp0 = blockIdx.x << 4;       // 16 points/block
    const int n_  = gp0 >> 13;
    const int b0  = gp0 & 8191;
    const int nbase_pt = n_ << 13;
    const int featbase = n_ << 18;         // n*8192*32

    // ================= Phase 1: each wave builds M for 4 points (fp32 VALU) =================
    #pragma unroll 1
    for (int pw = 0; pw < 4; ++pw) {
        const int p  = (w << 2) | pw;      // 0..15
        const int gp = gp0 + p;

        const int   abase = (gp << 5) | c;
        const int   idx   = neigh[abase];
        const float msk   = rmask[abase];
        const float cx = coords[gp * 3 + 0];
        const float cy = coords[gp * 3 + 1];
        const float cz = coords[gp * 3 + 2];
        const int   nb = nbase_pt + idx;
        const float dx = coords[nb * 3 + 0] - cx;
        const float dy = coords[nb * 3 + 1] - cy;
        const float dz = coords[nb * 3 + 2] - cz;
        const float r   = sqrtf(dx * dx + dy * dy + dz * dz);
        const float inv = 1.0f / (r + 1e-8f);
        const float x = dx * inv, y = dy * inv, z = dz * inv;
        const float Y0 = 0.28209479f;
        const float Y1 = 0.48860251f * x;
        const float Y2 = 0.48860251f * y;
        const float Y3 = 0.48860251f * z;
        const float Y4 = 1.09254843f * x * y;
        const float Y5 = 1.09254843f * y * z;
        const float Y6 = 0.31539157f * (3.0f * z * z - 1.0f);
        const float Y7 = 1.09254843f * x * z;
        const float Y8 = 0.54627421f * (x * x - y * y);
        const float t0 = (r - 0.5f) * 2.0f;
        const float t1 = (r - 1.0f) * 2.0f;
        const float t2 = (r - 1.5f) * 2.0f;
        const float t3 = (r - 2.0f) * 2.0f;
        const float rb0 = __expf(-t0 * t0) * msk;
        const float rb1 = __expf(-t1 * t1) * msk;
        const float rb2 = __expf(-t2 * t2) * msk;
        const float rb3 = __expf(-t3 * t3) * msk;

        if (lane < 32) {
            *(float4*)&geomY[w][c][0]    = make_float4(Y0, Y1, Y2, Y3);
            *(float4*)&geomY[w][c][4]    = make_float4(Y4, Y5, Y6, Y7);
            *(float4*)&geomR[w][c][0][0] = make_float4(rb0, rb1, Y8, 0.0f);
            *(float4*)&geomR[w][c][1][0] = make_float4(rb2, rb3, Y8, 0.0f);
            idxs[w][c] = idx;
        }
        // same-wave LDS write->read: DS pipe in-order per wave (validated in R1)

        float acc[18];
        #pragma unroll
        for (int j = 0; j < 18; ++j) acc[j] = 0.0f;

        #pragma unroll 8
        for (int a = 0; a < 32; ++a) {
            const int    ia   = idxs[w][a];
            const float  f    = inp_t[featbase + (ia << 5) + c];   // coalesced 128B line
            const float4 rbY8 = *(const float4*)&geomR[w][a][kh][0];
            const float4 y03  = *(const float4*)&geomY[w][a][0];
            const float4 y47  = *(const float4*)&geomY[w][a][4];
            const float fA = f * rbY8.x, fB = f * rbY8.y;
            acc[0] += fA * y03.x;   acc[9]  += fB * y03.x;
            acc[1] += fA * y03.y;   acc[10] += fB * y03.y;
            acc[2] += fA * y03.z;   acc[11] += fB * y03.z;
            acc[3] += fA * y03.w;   acc[12] += fB * y03.w;
            acc[4] += fA * y47.x;   acc[13] += fB * y47.x;
            acc[5] += fA * y47.y;   acc[14] += fB * y47.y;
            acc[6] += fA * y47.z;   acc[15] += fB * y47.z;
            acc[7] += fA * y47.w;   acc[16] += fB * y47.w;
            acc[8] += fA * rbY8.z;  acc[17] += fB * rbY8.z;
        }

        // store to Mb in MFMA-B layout; ck = c*36 + kh*18 + j (even base -> u32 pair packs)
        const int ckb = c * 36 + kh * 18;
        #pragma unroll
        for (int j9 = 0; j9 < 9; ++j9) {
            const int ck  = ckb + 2 * j9;
            const int kt  = ck >> 5;
            const int kin = ck & 31;
            const unsigned int pk = pack_bf16(acc[2 * j9], acc[2 * j9 + 1]);
            *(unsigned int*)&Mb[((kt * 16 + p) << 5) + kin] = pk;
        }
    }
    __syncthreads();

    // ============ Phase 2: out(32d x 16p) = W(32d x 1152) . M(1152 x 16p) via MFMA ============
    // wave w: dt = w>>1 (d-tile), kh2 = w&1 (K-half of 18 kt-steps)
    {
        const int dt  = w >> 1;
        const int kh2 = w & 1;
        const int l15 = lane & 15;
        const int q   = lane >> 4;
        f32x4 acc2 = {0.0f, 0.0f, 0.0f, 0.0f};
        const int kt0 = kh2 * 18;
        #pragma unroll 2
        for (int kt = kt0; kt < kt0 + 18; ++kt) {
            const bf16x8 af = *(const bf16x8*)&Wfrag[(((size_t)(kt * 2 + dt) * 64 + lane)) << 3];
            const bf16x8 bf = *(const bf16x8*)&Mb[((kt * 16 + l15) << 5) + (q << 3)];
            acc2 = __builtin_amdgcn_mfma_f32_16x16x32_bf16(af, bf, acc2, 0, 0, 0);
        }
        *(f32x4*)&Cp[(w * 64 + lane) * 4] = acc2;
    }
    __syncthreads();

    if (w < 2) {
        // wave w combines K-halves for d-tile dt2=w and stores
        const int dt2 = w;
        const f32x4 s0 = *(const f32x4*)&Cp[((dt2 * 2 + 0) * 64 + lane) * 4];
        const f32x4 s1 = *(const f32x4*)&Cp[((dt2 * 2 + 1) * 64 + lane) * 4];
        const int drow = dt2 * 16 + (lane >> 4) * 4;   // D row = (lane>>4)*4 + reg
        const int col  = b0 + (lane & 15);             // D col = lane&15 -> point
        #pragma unroll
        for (int rr = 0; rr < 4; ++rr) {
            out[(((n_ << 5) + drow + rr) << 13) + col] = s0[rr] + s1[rr];
        }
    }
}

extern "C" void kernel_launch(void* const* d_in, const int* in_sizes, int n_in,
                              void* d_out, int out_size, void* d_ws, size_t ws_size,
                              hipStream_t stream)
{
    const float* inp    = (const float*)d_in[0];
    const float* coords = (const float*)d_in[1];
    const float* rmask  = (const float*)d_in[2];
    const float* W      = (const float*)d_in[3];
    const int*   neigh  = (const int*)d_in[4];
    float*       outp   = (float*)d_out;

    float*          inp_t = (float*)d_ws;                                 // 4 MB
    unsigned short* Wfrag = (unsigned short*)((char*)d_ws + (4u << 20));  // 73.7 KB

    prep_kernel<<<1168, 256, 0, stream>>>(inp, W, inp_t, Wfrag);
    se3_main<<<2048, 256, 0, stream>>>(inp_t, coords, rmask, neigh, Wfrag, outp);
}

// Round 3
// 167.373 us; speedup vs baseline: 1.0869x; 1.0869x over previous
//
#include <hip/hip_runtime.h>
#include <hip/hip_bf16.h>

// Problem constants (fixed): n=4, b=8192, a=32, c_in=32, d_out=32,
// n_basis=36 (4 radii x 9 SH), ck=1152.
// inputs: [0] input (4,32,8192) f32, [1] coords (4,8192,3) f32,
//         [2] relative_mask (4,8192,32) f32, [3] W (32,32,36) f32,
//         [4] neighbors (4,8192,32) i32
// output: (4,32,8192) f32

typedef short bf16x8 __attribute__((ext_vector_type(8)));
typedef float f32x4  __attribute__((ext_vector_type(4)));

__device__ __forceinline__ unsigned int pack_bf16(float a, float b) {
    __hip_bfloat16 ha = __float2bfloat16(a);
    __hip_bfloat16 hb = __float2bfloat16(b);
    unsigned short ua = *reinterpret_cast<unsigned short*>(&ha);
    unsigned short ub = *reinterpret_cast<unsigned short*>(&hb);
    return ((unsigned int)ub << 16) | (unsigned int)ua;
}

__device__ __forceinline__ float bcast(float v, int srclane) {
    return __int_as_float(__builtin_amdgcn_readlane(__float_as_int(v), srclane));
}

// ---------------- prep: LDS-tiled transpose + W -> MFMA-A-fragment bf16 pack --------------
// Wfrag element t = ((kt*2+dt)*64 + l)*8 + j  holds  W[dt*16 + (l&15)][kt*32 + (l>>4)*8 + j]
__global__ __launch_bounds__(256) void prep_kernel(
    const float* __restrict__ inp, const float* __restrict__ W,
    float* __restrict__ inp_t, unsigned short* __restrict__ Wfrag)
{
    if (blockIdx.x < 1024) {
        // 32x32 tile transpose: (n,c,b) -> (n,b,c), coalesced both sides
        __shared__ float T[32][33];
        const int n  = blockIdx.x >> 8;          // 256 tiles per n
        const int b0 = (blockIdx.x & 255) << 5;
        const int bx = threadIdx.x & 31;
        const int cy = threadIdx.x >> 5;         // 0..7
        #pragma unroll
        for (int r = 0; r < 4; ++r) {
            const int cc = cy + r * 8;
            T[bx][cc] = inp[((n << 5) + cc) * 8192 + b0 + bx];
        }
        __syncthreads();
        #pragma unroll
        for (int r = 0; r < 4; ++r) {
            const int by = cy + r * 8;
            inp_t[((n << 13) + b0 + by) * 32 + bx] = T[by][bx];
        }
    } else {
        const int t = (blockIdx.x - 1024) * 256 + threadIdx.x;   // 0..36863
        if (t < 36 * 2 * 64 * 8) {
            const int j  = t & 7;
            const int l  = (t >> 3) & 63;
            const int dt = (t >> 9) & 1;
            const int kt = t >> 10;
            const int d  = dt * 16 + (l & 15);
            const int ck = kt * 32 + ((l >> 4) << 3) + j;
            __hip_bfloat16 h = __float2bfloat16(W[d * 1152 + ck]);
            Wfrag[t] = *reinterpret_cast<unsigned short*>(&h);
        }
    }
}

// ---------------- main fused kernel: 16 points/block, LDS-free phase-1 inner loop ----------
__global__ __launch_bounds__(256, 4) void se3_main(
    const float* __restrict__ inp_t, const float* __restrict__ coords,
    const float* __restrict__ rmask, const int* __restrict__ neigh,
    const unsigned short* __restrict__ Wfrag, float* __restrict__ out)
{
    // Only LDS: M in bf16, MFMA-B layout Mb[kt][p][kin], ck = kt*32+kin.
    // (Phase-2 partials Cp alias onto Mb behind a barrier.)
    __shared__ __align__(16) unsigned short Mb[36 * 16 * 32];   // 36,864 B -> 4 blocks/CU

    const int tid  = threadIdx.x;
    const int lane = tid & 63;
    const int w    = tid >> 6;       // wave 0..3
    const int c    = lane & 31;
    const bool khi = (lane >= 32);   // k-half: shells {2kh, 2kh+1}

    // XCD-aware swizzle: XCD pair {2n,2n+1} serves batch n (feat set ~4MB ~ L2/XCD).
    const int blk = blockIdx.x;
    const int n_  = (blk & 7) >> 1;                    // 0..3
    const int pos = ((blk >> 3) << 1) | (blk & 1);     // 0..511, unique per n
    const int b0  = pos << 4;
    const int gp0 = (n_ << 13) | b0;
    const int nbase_pt = n_ << 13;
    const float* __restrict__ inp_n = inp_t + ((size_t)n_ << 18);

    // ============ Phase 1: each wave builds M for 4 points (fp32 VALU, readlane bcast) ======
    #pragma unroll 1
    for (int pw = 0; pw < 4; ++pw) {
        const int p  = (w << 2) | pw;      // 0..15
        const int gp = gp0 + p;

        // geometry for neighbor a = c (halves duplicate; harmless)
        const int   abase = (gp << 5) | c;
        const int   idx   = neigh[abase];
        const float msk   = rmask[abase];
        const float cx = coords[gp * 3 + 0];
        const float cy = coords[gp * 3 + 1];
        const float cz = coords[gp * 3 + 2];
        const int   nb = nbase_pt + idx;
        const float dx = coords[nb * 3 + 0] - cx;
        const float dy = coords[nb * 3 + 1] - cy;
        const float dz = coords[nb * 3 + 2] - cz;
        const float r   = sqrtf(dx * dx + dy * dy + dz * dz);
        const float inv = 1.0f / (r + 1e-8f);
        const float x = dx * inv, y = dy * inv, z = dz * inv;
        const float Y0 = 0.28209479f;
        const float Y1 = 0.48860251f * x;
        const float Y2 = 0.48860251f * y;
        const float Y3 = 0.48860251f * z;
        const float Y4 = 1.09254843f * x * y;
        const float Y5 = 1.09254843f * y * z;
        const float Y6 = 0.31539157f * (3.0f * z * z - 1.0f);
        const float Y7 = 1.09254843f * x * z;
        const float Y8 = 0.54627421f * (x * x - y * y);
        const float t0 = (r - 0.5f) * 2.0f;
        const float t1 = (r - 1.0f) * 2.0f;
        const float t2 = (r - 1.5f) * 2.0f;
        const float t3 = (r - 2.0f) * 2.0f;
        const float rb0 = __expf(-t0 * t0) * msk;
        const float rb1 = __expf(-t1 * t1) * msk;
        const float rb2 = __expf(-t2 * t2) * msk;
        const float rb3 = __expf(-t3 * t3) * msk;

        // -------- prefetch all 32 feat rows (independent scalar-base loads) --------
        float f[32];
        #pragma unroll
        for (int a = 0; a < 32; ++a) {
            const int ia = __builtin_amdgcn_readlane(idx, a);   // uniform -> SGPR
            f[a] = inp_n[((size_t)(unsigned)ia << 5) + c];      // coalesced 128B line
        }

        float acc[18];
        #pragma unroll
        for (int j = 0; j < 18; ++j) acc[j] = 0.0f;

        // -------- FMA loop: geometry broadcast via readlane (no LDS) --------
        #pragma unroll
        for (int a = 0; a < 32; ++a) {
            const float srb0 = bcast(rb0, a);
            const float srb1 = bcast(rb1, a);
            const float srb2 = bcast(rb2, a);
            const float srb3 = bcast(rb3, a);
            const float sY0  = bcast(Y0, a);
            const float sY1  = bcast(Y1, a);
            const float sY2  = bcast(Y2, a);
            const float sY3  = bcast(Y3, a);
            const float sY4  = bcast(Y4, a);
            const float sY5  = bcast(Y5, a);
            const float sY6  = bcast(Y6, a);
            const float sY7  = bcast(Y7, a);
            const float sY8  = bcast(Y8, a);
            const float rbA = khi ? srb2 : srb0;
            const float rbB = khi ? srb3 : srb1;
            const float fA = f[a] * rbA;
            const float fB = f[a] * rbB;
            acc[0]  += fA * sY0;   acc[9]  += fB * sY0;
            acc[1]  += fA * sY1;   acc[10] += fB * sY1;
            acc[2]  += fA * sY2;   acc[11] += fB * sY2;
            acc[3]  += fA * sY3;   acc[12] += fB * sY3;
            acc[4]  += fA * sY4;   acc[13] += fB * sY4;
            acc[5]  += fA * sY5;   acc[14] += fB * sY5;
            acc[6]  += fA * sY6;   acc[15] += fB * sY6;
            acc[7]  += fA * sY7;   acc[16] += fB * sY7;
            acc[8]  += fA * sY8;   acc[17] += fB * sY8;
        }

        // store to Mb in MFMA-B layout; ck = c*36 + kh*18 + j (even base -> u32 pair packs)
        const int kh  = khi ? 1 : 0;
        const int ckb = c * 36 + kh * 18;
        #pragma unroll
        for (int j9 = 0; j9 < 9; ++j9) {
            const int ck  = ckb + 2 * j9;
            const int kt  = ck >> 5;
            const int kin = ck & 31;
            const unsigned int pk = pack_bf16(acc[2 * j9], acc[2 * j9 + 1]);
            *(unsigned int*)&Mb[((kt * 16 + p) << 5) + kin] = pk;
        }
    }
    __syncthreads();

    // ============ Phase 2: out(32d x 16p) = W(32d x 1152) . M(1152 x 16p) via MFMA ============
    // wave w: dt = w>>1 (d-tile), kh2 = w&1 (K-half of 18 kt-steps)
    float* Cp = reinterpret_cast<float*>(Mb);   // alias; written only after barrier below
    {
        const int dt  = w >> 1;
        const int kh2 = w & 1;
        const int l15 = lane & 15;
        const int q   = lane >> 4;
        f32x4 acc2 = {0.0f, 0.0f, 0.0f, 0.0f};
        const int kt0 = kh2 * 18;
        #pragma unroll 2
        for (int kt = kt0; kt < kt0 + 18; ++kt) {
            const bf16x8 af = *(const bf16x8*)&Wfrag[(((size_t)(kt * 2 + dt) * 64 + lane)) << 3];
            const bf16x8 bf = *(const bf16x8*)&Mb[((kt * 16 + l15) << 5) + (q << 3)];
            acc2 = __builtin_amdgcn_mfma_f32_16x16x32_bf16(af, bf, acc2, 0, 0, 0);
        }
        __syncthreads();   // all Mb reads complete before aliasing as Cp
        *(f32x4*)&Cp[(w * 64 + lane) * 4] = acc2;
    }
    __syncthreads();

    if (w < 2) {
        // wave w combines K-halves for d-tile dt2=w and stores
        const int dt2 = w;
        const f32x4 s0 = *(const f32x4*)&Cp[((dt2 * 2 + 0) * 64 + lane) * 4];
        const f32x4 s1 = *(const f32x4*)&Cp[((dt2 * 2 + 1) * 64 + lane) * 4];
        const int drow = dt2 * 16 + (lane >> 4) * 4;   // D row = (lane>>4)*4 + reg
        const int col  = b0 + (lane & 15);             // D col = lane&15 -> point
        #pragma unroll
        for (int rr = 0; rr < 4; ++rr) {
            out[(((n_ << 5) + drow + rr) << 13) + col] = s0[rr] + s1[rr];
        }
    }
}

extern "C" void kernel_launch(void* const* d_in, const int* in_sizes, int n_in,
                              void* d_out, int out_size, void* d_ws, size_t ws_size,
                              hipStream_t stream)
{
    const float* inp    = (const float*)d_in[0];
    const float* coords = (const float*)d_in[1];
    const float* rmask  = (const float*)d_in[2];
    const float* W      = (const float*)d_in[3];
    const int*   neigh  = (const int*)d_in[4];
    float*       outp   = (float*)d_out;

    float*          inp_t = (float*)d_ws;                                 // 4 MB
    unsigned short* Wfrag = (unsigned short*)((char*)d_ws + (4u << 20));  // 73.7 KB

    prep_kernel<<<1168, 256, 0, stream>>>(inp, W, inp_t, Wfrag);
    se3_main<<<2048, 256, 0, stream>>>(inp_t, coords, rmask, neigh, Wfrag, outp);
}

// Round 5
// 104.219 us; speedup vs baseline: 1.7455x; 1.6060x over previous
//
#include <hip/hip_runtime.h>
#include <hip/hip_bf16.h>

// Problem constants (fixed): n=4, b=8192, a=32, c_in=32, d_out=32,
// n_basis=36 (4 radii x 9 SH), ck=1152.
// inputs: [0] input (4,32,8192) f32, [1] coords (4,8192,3) f32,
//         [2] relative_mask (4,8192,32) f32, [3] W (32,32,36) f32,
//         [4] neighbors (4,8192,32) i32
// output: (4,32,8192) f32
//
// R4b: phase-1 contraction M[c,k'] = sum_a feat[a,c]*basis[a,k'] on MFMA
// (6x mfma_f32_16x16x32_f16 per point). fp16 throughout (8x finer than bf16).
// K-order for phase 2 re-permuted to kappa = k'*32 + c so phase-1 D-registers
// pair-pack into b32 LDS writes; Wfrag prep built in the same kappa order.
// (R4 failed to compile: cvt_pkrtz returns __fp16x2, not _Float16x2 — fixed.)

typedef _Float16 f16x8 __attribute__((ext_vector_type(8)));
typedef _Float16 f16x4 __attribute__((ext_vector_type(4)));
typedef __fp16   h16x2 __attribute__((ext_vector_type(2)));
typedef float    f32x4 __attribute__((ext_vector_type(4)));
typedef unsigned int u32;

__device__ __forceinline__ u32 pk16(float a, float b) {
    union { h16x2 v; u32 u; } cv;
    cv.v = __builtin_amdgcn_cvt_pkrtz(a, b);
    return cv.u;
}

// ---------------- prep: LDS-tiled transpose + W -> MFMA-A fragments (f16, kappa order) -----
// Wfrag[t], t = ((kt*2+dt)*64 + l)*8 + j  holds  W[d][c*36 + k'] as f16, where
// d = dt*16 + (l&15), kappa = kt*32 + (l>>4)*8 + j, c = kappa&31 = (l>>4)*8+j, k' = kt.
__global__ __launch_bounds__(256) void prep_kernel(
    const float* __restrict__ inp, const float* __restrict__ W,
    float* __restrict__ inp_t, unsigned short* __restrict__ Wfrag)
{
    if (blockIdx.x < 1024) {
        // 32x32 tile transpose: (n,c,b) -> (n,b,c), coalesced both sides
        __shared__ float T[32][33];
        const int n  = blockIdx.x >> 8;
        const int b0 = (blockIdx.x & 255) << 5;
        const int bx = threadIdx.x & 31;
        const int cy = threadIdx.x >> 5;   // 0..7
        #pragma unroll
        for (int r = 0; r < 4; ++r) {
            const int cc = cy + r * 8;
            T[bx][cc] = inp[((n << 5) + cc) * 8192 + b0 + bx];
        }
        __syncthreads();
        #pragma unroll
        for (int r = 0; r < 4; ++r) {
            const int by = cy + r * 8;
            inp_t[((n << 13) + b0 + by) * 32 + bx] = T[by][bx];
        }
    } else {
        const int t = (blockIdx.x - 1024) * 256 + threadIdx.x;   // 0..36863
        if (t < 36 * 2 * 64 * 8) {
            const int j  = t & 7;
            const int l  = (t >> 3) & 63;
            const int dt = (t >> 9) & 1;
            const int kt = t >> 10;                  // k' = 0..35
            const int d  = dt * 16 + (l & 15);
            const int c  = ((l >> 4) << 3) + j;
            const _Float16 hv = (_Float16)W[d * 1152 + c * 36 + kt];
            Wfrag[t] = __builtin_bit_cast(unsigned short, hv);
        }
    }
}

// ---------------- main fused kernel: 16 points/block, MFMA both phases ----------------
__global__ __launch_bounds__(256, 3) void se3_main(
    const float* __restrict__ inp_t, const float* __restrict__ coords,
    const float* __restrict__ rmask, const int* __restrict__ neigh,
    const unsigned short* __restrict__ Wfrag, float* __restrict__ out)
{
    // Mb[k'=0..35][p=0..15][c=0..31] f16; p-row 72B (36 us), plane 1160B (580 us).
    // Plane pad 8B makes phase-2 b64 reads conflict-free.
    __shared__ __align__(16) unsigned short Mb_s[36 * 580];   // 41,760 B
    // basis^T per wave: bas[phys_row 0..36][a 0..31] f16, row 72B (36 us).
    // phys = 2t + h interleave -> u16 writes 2-way free; row 36 = garbage pad.
    __shared__ __align__(16) unsigned short bas[4][37 * 36];  // 10,656 B
    __shared__ int idxs[16][32];                              //  2,048 B
    // total 54,464 B -> 3 blocks/CU

    const int tid  = threadIdx.x;
    const int lane = tid & 63;
    const int w    = tid >> 6;      // wave 0..3
    const int l15  = lane & 15;
    const int q    = lane >> 4;     // 0..3
    const int a_   = lane & 31;
    const int h_   = lane >> 5;     // k-half of basis build

    // XCD-aware swizzle (R3): XCD pair {2n,2n+1} serves batch n
    const int blk = blockIdx.x;
    const int n_  = (blk & 7) >> 1;
    const int pos = ((blk >> 3) << 1) | (blk & 1);
    const int b0  = pos << 4;
    const int gp0 = (n_ << 13) | b0;
    const int nbase_pt = n_ << 13;
    const float* __restrict__ inp_n = inp_t + ((size_t)n_ << 18);

    unsigned short* basw = &bas[w][0];

    // basis^T read rows per nt (A/B-frag needs k' = nt*16 + l15):
    // phys(k') = k'<18 ? 2k' : (k'<36 ? 2k'-35 : 36)
    const int ph0 = 2 * l15;
    const int ph1 = (l15 < 2) ? (32 + 2 * l15) : (2 * l15 - 3);
    const int ph2 = (l15 < 4) ? (29 + 2 * l15) : 36;
    const int offB0 = ph0 * 36 + (q << 3);
    const int offB1 = ph1 * 36 + (q << 3);
    const int offB2 = ph2 * 36 + (q << 3);

    // ================= Phase 1: one point per pass, 4 passes per wave =================
    #pragma unroll 1
    for (int pw = 0; pw < 4; ++pw) {
        const int p  = (w << 2) | pw;    // 0..15
        const int gp = gp0 + p;

        // ---- geometry: lanes 0..31 = neighbors, lanes 32..63 duplicate ----
        const int   abase = (gp << 5) | a_;
        const int   idx   = neigh[abase];
        const float msk   = rmask[abase];
        const float cx = coords[gp * 3 + 0];
        const float cy = coords[gp * 3 + 1];
        const float cz = coords[gp * 3 + 2];
        const int   nb = nbase_pt + idx;
        const float dx = coords[nb * 3 + 0] - cx;
        const float dy = coords[nb * 3 + 1] - cy;
        const float dz = coords[nb * 3 + 2] - cz;
        const float r   = sqrtf(dx * dx + dy * dy + dz * dz);
        const float inv = 1.0f / (r + 1e-8f);
        const float x = dx * inv, y = dy * inv, z = dz * inv;
        float Yv[9];
        Yv[0] = 0.28209479f;
        Yv[1] = 0.48860251f * x;
        Yv[2] = 0.48860251f * y;
        Yv[3] = 0.48860251f * z;
        Yv[4] = 1.09254843f * x * y;
        Yv[5] = 1.09254843f * y * z;
        Yv[6] = 0.31539157f * (3.0f * z * z - 1.0f);
        Yv[7] = 1.09254843f * x * z;
        Yv[8] = 0.54627421f * (x * x - y * y);
        const float t0 = (r - 0.5f) * 2.0f;
        const float t1 = (r - 1.0f) * 2.0f;
        const float t2 = (r - 1.5f) * 2.0f;
        const float t3 = (r - 2.0f) * 2.0f;
        const float rb0 = __expf(-t0 * t0) * msk;
        const float rb1 = __expf(-t1 * t1) * msk;
        const float rb2 = __expf(-t2 * t2) * msk;
        const float rb3 = __expf(-t3 * t3) * msk;

        if (lane < 32) idxs[p][a_] = idx;

        // ---- basis^T store: k = 18h + t, phys row = 2t + h ----
        const float rbA = h_ ? rb2 : rb0;
        const float rbB = h_ ? rb3 : rb1;
        #pragma unroll
        for (int t = 0; t < 18; ++t) {
            const float v = (t < 9) ? rbA * Yv[t] : rbB * Yv[t - 9];
            const _Float16 hv = (_Float16)v;
            basw[(2 * t + h_) * 36 + a_] = __builtin_bit_cast(unsigned short, hv);
        }

        // ---- feat A-fragments straight from global: A[m=c][k=a] ----
        int ridx[8];
        #pragma unroll
        for (int j = 0; j < 8; ++j) ridx[j] = idxs[p][(q << 3) + j];
        float fv0[8], fv1[8];
        #pragma unroll
        for (int j = 0; j < 8; ++j) {
            const float* rp2 = inp_n + (((unsigned)ridx[j]) << 5) + l15;
            fv0[j] = rp2[0];     // c = l15      (mt=0)
            fv1[j] = rp2[16];    // c = l15 + 16 (mt=1)
        }
        union { f16x8 v; u32 u[4]; } af0, af1;
        #pragma unroll
        for (int j4 = 0; j4 < 4; ++j4) {
            af0.u[j4] = pk16(fv0[2 * j4], fv0[2 * j4 + 1]);
            af1.u[j4] = pk16(fv1[2 * j4], fv1[2 * j4 + 1]);
        }

        // ---- basis B-fragments from LDS: B[k=a][n=k'] (b64 pairs, conflict-free) ----
        f16x4 blo, bhi;
        blo = *(const f16x4*)&basw[offB0]; bhi = *(const f16x4*)&basw[offB0 + 4];
        const f16x8 Bf0 = __builtin_shufflevector(blo, bhi, 0, 1, 2, 3, 4, 5, 6, 7);
        blo = *(const f16x4*)&basw[offB1]; bhi = *(const f16x4*)&basw[offB1 + 4];
        const f16x8 Bf1 = __builtin_shufflevector(blo, bhi, 0, 1, 2, 3, 4, 5, 6, 7);
        blo = *(const f16x4*)&basw[offB2]; bhi = *(const f16x4*)&basw[offB2 + 4];
        const f16x8 Bf2 = __builtin_shufflevector(blo, bhi, 0, 1, 2, 3, 4, 5, 6, 7);

        // ---- 6 MFMAs: D[mt][nt], rows = c-local (q*4+reg), cols = k'-local (l15) ----
        const f32x4 z4 = {0.0f, 0.0f, 0.0f, 0.0f};
        f32x4 D00 = __builtin_amdgcn_mfma_f32_16x16x32_f16(af0.v, Bf0, z4, 0, 0, 0);
        f32x4 D01 = __builtin_amdgcn_mfma_f32_16x16x32_f16(af0.v, Bf1, z4, 0, 0, 0);
        f32x4 D02 = __builtin_amdgcn_mfma_f32_16x16x32_f16(af0.v, Bf2, z4, 0, 0, 0);
        f32x4 D10 = __builtin_amdgcn_mfma_f32_16x16x32_f16(af1.v, Bf0, z4, 0, 0, 0);
        f32x4 D11 = __builtin_amdgcn_mfma_f32_16x16x32_f16(af1.v, Bf1, z4, 0, 0, 0);
        f32x4 D12 = __builtin_amdgcn_mfma_f32_16x16x32_f16(af1.v, Bf2, z4, 0, 0, 0);

        // ---- D -> Mb[k'][p][c]: reg pairs = consecutive c -> single b32 writes ----
        {
            const int rowp = p * 36 + (q << 2);
            const int b_0 = (0 * 16 + l15) * 580 + rowp;        // nt=0
            const int b_1 = (1 * 16 + l15) * 580 + rowp;        // nt=1 (k'=16+l15)
            *(u32*)&Mb_s[b_0]          = pk16(D00[0], D00[1]);
            *(u32*)&Mb_s[b_0 + 2]      = pk16(D00[2], D00[3]);
            *(u32*)&Mb_s[b_0 + 16]     = pk16(D10[0], D10[1]);
            *(u32*)&Mb_s[b_0 + 18]     = pk16(D10[2], D10[3]);
            *(u32*)&Mb_s[b_1]          = pk16(D01[0], D01[1]);
            *(u32*)&Mb_s[b_1 + 2]      = pk16(D01[2], D01[3]);
            *(u32*)&Mb_s[b_1 + 16]     = pk16(D11[0], D11[1]);
            *(u32*)&Mb_s[b_1 + 18]     = pk16(D11[2], D11[3]);
            if (l15 < 4) {   // nt=2: only k' = 32..35 valid
                const int b_2 = (32 + l15) * 580 + rowp;
                *(u32*)&Mb_s[b_2]      = pk16(D02[0], D02[1]);
                *(u32*)&Mb_s[b_2 + 2]  = pk16(D02[2], D02[3]);
                *(u32*)&Mb_s[b_2 + 16] = pk16(D12[0], D12[1]);
                *(u32*)&Mb_s[b_2 + 18] = pk16(D12[2], D12[3]);
            }
        }
    }
    __syncthreads();

    // ============ Phase 2: out(32d x 16p) = W . M via MFMA, kappa = k'*32 + c ============
    {
        const int dt  = w >> 1;
        const int kh2 = w & 1;
        f32x4 acc2 = {0.0f, 0.0f, 0.0f, 0.0f};
        const int kt0 = kh2 * 18;
        #pragma unroll 2
        for (int kt = kt0; kt < kt0 + 18; ++kt) {
            const f16x8 af = *(const f16x8*)&Wfrag[((size_t)((kt * 2 + dt) * 64 + lane)) << 3];
            const int mbase = kt * 580 + l15 * 36 + (q << 3);
            const f16x4 mlo = *(const f16x4*)&Mb_s[mbase];
            const f16x4 mhi = *(const f16x4*)&Mb_s[mbase + 4];
            const f16x8 bf  = __builtin_shufflevector(mlo, mhi, 0, 1, 2, 3, 4, 5, 6, 7);
            acc2 = __builtin_amdgcn_mfma_f32_16x16x32_f16(af, bf, acc2, 0, 0, 0);
        }
        __syncthreads();   // all Mb reads done -> alias as Cp
        float* Cp = reinterpret_cast<float*>(Mb_s);
        *(f32x4*)&Cp[(w * 64 + lane) * 4] = acc2;
    }
    __syncthreads();

    if (w < 2) {
        const float* Cp = reinterpret_cast<const float*>(Mb_s);
        const int dt2 = w;
        const f32x4 s0 = *(const f32x4*)&Cp[((dt2 * 2 + 0) * 64 + lane) * 4];
        const f32x4 s1 = *(const f32x4*)&Cp[((dt2 * 2 + 1) * 64 + lane) * 4];
        const int drow = dt2 * 16 + (lane >> 4) * 4;   // D row = (lane>>4)*4 + reg
        const int col  = b0 + (lane & 15);
        #pragma unroll
        for (int rr = 0; rr < 4; ++rr) {
            out[(((n_ << 5) + drow + rr) << 13) + col] = s0[rr] + s1[rr];
        }
    }
}

extern "C" void kernel_launch(void* const* d_in, const int* in_sizes, int n_in,
                              void* d_out, int out_size, void* d_ws, size_t ws_size,
                              hipStream_t stream)
{
    const float* inp    = (const float*)d_in[0];
    const float* coords = (const float*)d_in[1];
    const float* rmask  = (const float*)d_in[2];
    const float* W      = (const float*)d_in[3];
    const int*   neigh  = (const int*)d_in[4];
    float*       outp   = (float*)d_out;

    float*          inp_t = (float*)d_ws;                                 // 4 MB
    unsigned short* Wfrag = (unsigned short*)((char*)d_ws + (4u << 20));  // 73.7 KB

    prep_kernel<<<1168, 256, 0, stream>>>(inp, W, inp_t, Wfrag);
    se3_main<<<2048, 256, 0, stream>>>(inp_t, coords, rmask, neigh, Wfrag, outp);
}

// Round 6
// 93.040 us; speedup vs baseline: 1.9552x; 1.1202x over previous
//
#include <hip/hip_runtime.h>
#include <hip/hip_bf16.h>

// Problem constants (fixed): n=4, b=8192, a=32, c_in=32, d_out=32,
// n_basis=36 (4 radii x 9 SH), ck=1152.
// inputs: [0] input (4,32,8192) f32, [1] coords (4,8192,3) f32,
//         [2] relative_mask (4,8192,32) f32, [3] W (32,32,36) f32,
//         [4] neighbors (4,8192,32) i32
// output: (4,32,8192) f32
//
// R6: latency-hiding round. 512-thread blocks (8 waves), 16 points/block,
// 2 passes/wave (was 4), per-wave bas buffers; LDS 73.3 KB -> 2 blocks/CU
// = 16 waves/CU (R5 was stuck at 8: 54.8 KB x3 > 160 KB). All global loads
// for both passes hoisted; geometry-B VALU overlaps MFMA-A. Phase 2 spread
// over all 8 waves (dt x 9-kt segment) + 4-way partial reduce.

typedef _Float16 f16x8 __attribute__((ext_vector_type(8)));
typedef _Float16 f16x4 __attribute__((ext_vector_type(4)));
typedef __fp16   h16x2 __attribute__((ext_vector_type(2)));
typedef float    f32x4 __attribute__((ext_vector_type(4)));
typedef unsigned int u32;

__device__ __forceinline__ u32 pk16(float a, float b) {
    union { h16x2 v; u32 u; } cv;
    cv.v = __builtin_amdgcn_cvt_pkrtz(a, b);
    return cv.u;
}
__device__ __forceinline__ unsigned short f16bits(float v) {
    const _Float16 hv = (_Float16)v;
    return __builtin_bit_cast(unsigned short, hv);
}

// geometry: SH l=0..2 and the h-half radial pair (mask folded in)
__device__ __forceinline__ void geom(float dx, float dy, float dz, float msk, int h_,
                                     float Y[9], float& rbA, float& rbB) {
    const float r   = sqrtf(dx * dx + dy * dy + dz * dz);
    const float inv = 1.0f / (r + 1e-8f);
    const float x = dx * inv, y = dy * inv, z = dz * inv;
    Y[0] = 0.28209479f;
    Y[1] = 0.48860251f * x;
    Y[2] = 0.48860251f * y;
    Y[3] = 0.48860251f * z;
    Y[4] = 1.09254843f * x * y;
    Y[5] = 1.09254843f * y * z;
    Y[6] = 0.31539157f * (3.0f * z * z - 1.0f);
    Y[7] = 1.09254843f * x * z;
    Y[8] = 0.54627421f * (x * x - y * y);
    const float t0 = (r - 0.5f) * 2.0f;
    const float t1 = (r - 1.0f) * 2.0f;
    const float t2 = (r - 1.5f) * 2.0f;
    const float t3 = (r - 2.0f) * 2.0f;
    const float rb0 = __expf(-t0 * t0) * msk;
    const float rb1 = __expf(-t1 * t1) * msk;
    const float rb2 = __expf(-t2 * t2) * msk;
    const float rb3 = __expf(-t3 * t3) * msk;
    rbA = h_ ? rb2 : rb0;
    rbB = h_ ? rb3 : rb1;
}

// ---------------- prep: LDS-tiled transpose + W -> MFMA-A fragments (f16, kappa order) -----
// Wfrag[t], t = ((kt*2+dt)*64 + l)*8 + j  holds  W[d][c*36 + k'] as f16, where
// d = dt*16 + (l&15), c = (l>>4)*8+j, k' = kt.
__global__ __launch_bounds__(256) void prep_kernel(
    const float* __restrict__ inp, const float* __restrict__ W,
    float* __restrict__ inp_t, unsigned short* __restrict__ Wfrag)
{
    if (blockIdx.x < 1024) {
        __shared__ float T[32][33];
        const int n  = blockIdx.x >> 8;
        const int b0 = (blockIdx.x & 255) << 5;
        const int bx = threadIdx.x & 31;
        const int cy = threadIdx.x >> 5;   // 0..7
        #pragma unroll
        for (int r = 0; r < 4; ++r) {
            const int cc = cy + r * 8;
            T[bx][cc] = inp[((n << 5) + cc) * 8192 + b0 + bx];
        }
        __syncthreads();
        #pragma unroll
        for (int r = 0; r < 4; ++r) {
            const int by = cy + r * 8;
            inp_t[((n << 13) + b0 + by) * 32 + bx] = T[by][bx];
        }
    } else {
        const int t = (blockIdx.x - 1024) * 256 + threadIdx.x;   // 0..36863
        if (t < 36 * 2 * 64 * 8) {
            const int j  = t & 7;
            const int l  = (t >> 3) & 63;
            const int dt = (t >> 9) & 1;
            const int kt = t >> 10;                  // k' = 0..35
            const int d  = dt * 16 + (l & 15);
            const int c  = ((l >> 4) << 3) + j;
            Wfrag[t] = f16bits(W[d * 1152 + c * 36 + kt]);
        }
    }
}

// ---------------- main fused kernel: 512 threads, 16 points/block, 2 passes/wave ----------
__global__ __launch_bounds__(512, 4) void se3_main(
    const float* __restrict__ inp_t, const float* __restrict__ coords,
    const float* __restrict__ rmask, const int* __restrict__ neigh,
    const unsigned short* __restrict__ Wfrag, float* __restrict__ out)
{
    // Mb[k'=0..35][p=0..15][c=0..31] f16; p-row 72B, plane 1160B (580 us, 8B pad).
    __shared__ __align__(16) unsigned short Mb_s[36 * 580];   // 41,760 B
    // basis^T per wave: phys = 2t + h interleave, row 72B, row 36 = garbage pad.
    __shared__ __align__(16) unsigned short bas[8][37 * 36];  // 21,312 B
    __shared__ int idxs[16][32];                              //  2,048 B
    __shared__ __align__(16) float Cp[8 * 64 * 4];            //  8,192 B
    // total 73,312 B -> 2 blocks/CU = 16 waves/CU

    const int tid  = threadIdx.x;
    const int lane = tid & 63;
    const int w    = tid >> 6;      // wave 0..7
    const int l15  = lane & 15;
    const int q    = lane >> 4;     // 0..3
    const int a_   = lane & 31;
    const int h_   = lane >> 5;

    // XCD-aware swizzle: XCD pair {2n,2n+1} serves batch n
    const int blk = blockIdx.x;
    const int n_  = (blk & 7) >> 1;
    const int pos = ((blk >> 3) << 1) | (blk & 1);
    const int b0  = pos << 4;
    const int gp0 = (n_ << 13) | b0;
    const int nbase_pt = n_ << 13;
    const float* __restrict__ inp_n = inp_t + ((size_t)n_ << 18);

    unsigned short* basw = &bas[w][0];

    // basis^T read rows per nt: phys(k') = k'<18 ? 2k' : (k'<36 ? 2k'-35 : 36)
    const int ph0 = 2 * l15;
    const int ph1 = (l15 < 2) ? (32 + 2 * l15) : (2 * l15 - 3);
    const int ph2 = (l15 < 4) ? (29 + 2 * l15) : 36;
    const int offB0 = ph0 * 36 + (q << 3);
    const int offB1 = ph1 * 36 + (q << 3);
    const int offB2 = ph2 * 36 + (q << 3);

    const int pA = w << 1, pB = pA | 1;
    const int gpA = gp0 + pA, gpB = gp0 + pB;

    // ================= hoisted global loads (both passes) =================
    const int   idxA = neigh[(gpA << 5) | a_];
    const int   idxB = neigh[(gpB << 5) | a_];
    const float mskA = rmask[(gpA << 5) | a_];
    const float mskB = rmask[(gpB << 5) | a_];
    const float cxA = coords[gpA * 3 + 0], cyA = coords[gpA * 3 + 1], czA = coords[gpA * 3 + 2];
    const float cxB = coords[gpB * 3 + 0], cyB = coords[gpB * 3 + 1], czB = coords[gpB * 3 + 2];
    if (lane < 32) { idxs[pA][a_] = idxA; idxs[pB][a_] = idxB; }
    const int nbA = (nbase_pt + idxA) * 3;
    const int nbB = (nbase_pt + idxB) * 3;
    const float dxA = coords[nbA + 0] - cxA, dyA = coords[nbA + 1] - cyA, dzA = coords[nbA + 2] - czA;
    const float dxB = coords[nbB + 0] - cxB, dyB = coords[nbB + 1] - cyB, dzB = coords[nbB + 2] - czB;

    // feat gathers for both passes (ridx via same-wave LDS, in-order DS)
    float fA0[8], fA1[8], fB0[8], fB1[8];
    #pragma unroll
    for (int j = 0; j < 8; ++j) {
        const int ri = idxs[pA][(q << 3) + j];
        const float* rp = inp_n + (((unsigned)ri) << 5) + l15;
        fA0[j] = rp[0]; fA1[j] = rp[16];
    }
    #pragma unroll
    for (int j = 0; j < 8; ++j) {
        const int ri = idxs[pB][(q << 3) + j];
        const float* rp = inp_n + (((unsigned)ri) << 5) + l15;
        fB0[j] = rp[0]; fB1[j] = rp[16];
    }

    // ================= geometry (VALU, overlaps the gathers) =================
    float YA[9], YB[9], rbA_A, rbB_A, rbA_B, rbB_B;
    geom(dxA, dyA, dzA, mskA, h_, YA, rbA_A, rbB_A);
    geom(dxB, dyB, dzB, mskB, h_, YB, rbA_B, rbB_B);

    // bas-A writes: k = 18h + t, phys row = 2t + h
    #pragma unroll
    for (int t = 0; t < 18; ++t) {
        const float v = (t < 9) ? rbA_A * YA[t] : rbB_A * YA[t - 9];
        basw[(2 * t + h_) * 36 + a_] = f16bits(v);
    }

    // Bf-A reads (b64, conflict-free); must issue before bas-B writes (same-wave DS order)
    f16x4 blo, bhi;
    blo = *(const f16x4*)&basw[offB0]; bhi = *(const f16x4*)&basw[offB0 + 4];
    const f16x8 BfA0 = __builtin_shufflevector(blo, bhi, 0, 1, 2, 3, 4, 5, 6, 7);
    blo = *(const f16x4*)&basw[offB1]; bhi = *(const f16x4*)&basw[offB1 + 4];
    const f16x8 BfA1 = __builtin_shufflevector(blo, bhi, 0, 1, 2, 3, 4, 5, 6, 7);
    blo = *(const f16x4*)&basw[offB2]; bhi = *(const f16x4*)&basw[offB2 + 4];
    const f16x8 BfA2 = __builtin_shufflevector(blo, bhi, 0, 1, 2, 3, 4, 5, 6, 7);

    // pack A-fragments, MFMA A
    union { f16x8 v; u32 u[4]; } afA0, afA1, afB0, afB1;
    #pragma unroll
    for (int j4 = 0; j4 < 4; ++j4) {
        afA0.u[j4] = pk16(fA0[2 * j4], fA0[2 * j4 + 1]);
        afA1.u[j4] = pk16(fA1[2 * j4], fA1[2 * j4 + 1]);
    }
    const f32x4 z4 = {0.0f, 0.0f, 0.0f, 0.0f};
    f32x4 DA00 = __builtin_amdgcn_mfma_f32_16x16x32_f16(afA0.v, BfA0, z4, 0, 0, 0);
    f32x4 DA01 = __builtin_amdgcn_mfma_f32_16x16x32_f16(afA0.v, BfA1, z4, 0, 0, 0);
    f32x4 DA02 = __builtin_amdgcn_mfma_f32_16x16x32_f16(afA0.v, BfA2, z4, 0, 0, 0);
    f32x4 DA10 = __builtin_amdgcn_mfma_f32_16x16x32_f16(afA1.v, BfA0, z4, 0, 0, 0);
    f32x4 DA11 = __builtin_amdgcn_mfma_f32_16x16x32_f16(afA1.v, BfA1, z4, 0, 0, 0);
    f32x4 DA12 = __builtin_amdgcn_mfma_f32_16x16x32_f16(afA1.v, BfA2, z4, 0, 0, 0);

    // bas-B writes (after Bf-A reads in program order)
    #pragma unroll
    for (int t = 0; t < 18; ++t) {
        const float v = (t < 9) ? rbA_B * YB[t] : rbB_B * YB[t - 9];
        basw[(2 * t + h_) * 36 + a_] = f16bits(v);
    }
    blo = *(const f16x4*)&basw[offB0]; bhi = *(const f16x4*)&basw[offB0 + 4];
    const f16x8 BfB0 = __builtin_shufflevector(blo, bhi, 0, 1, 2, 3, 4, 5, 6, 7);
    blo = *(const f16x4*)&basw[offB1]; bhi = *(const f16x4*)&basw[offB1 + 4];
    const f16x8 BfB1 = __builtin_shufflevector(blo, bhi, 0, 1, 2, 3, 4, 5, 6, 7);
    blo = *(const f16x4*)&basw[offB2]; bhi = *(const f16x4*)&basw[offB2 + 4];
    const f16x8 BfB2 = __builtin_shufflevector(blo, bhi, 0, 1, 2, 3, 4, 5, 6, 7);

    #pragma unroll
    for (int j4 = 0; j4 < 4; ++j4) {
        afB0.u[j4] = pk16(fB0[2 * j4], fB0[2 * j4 + 1]);
        afB1.u[j4] = pk16(fB1[2 * j4], fB1[2 * j4 + 1]);
    }
    f32x4 DB00 = __builtin_amdgcn_mfma_f32_16x16x32_f16(afB0.v, BfB0, z4, 0, 0, 0);
    f32x4 DB01 = __builtin_amdgcn_mfma_f32_16x16x32_f16(afB0.v, BfB1, z4, 0, 0, 0);
    f32x4 DB02 = __builtin_amdgcn_mfma_f32_16x16x32_f16(afB0.v, BfB2, z4, 0, 0, 0);
    f32x4 DB10 = __builtin_amdgcn_mfma_f32_16x16x32_f16(afB1.v, BfB0, z4, 0, 0, 0);
    f32x4 DB11 = __builtin_amdgcn_mfma_f32_16x16x32_f16(afB1.v, BfB1, z4, 0, 0, 0);
    f32x4 DB12 = __builtin_amdgcn_mfma_f32_16x16x32_f16(afB1.v, BfB2, z4, 0, 0, 0);

    // ---- D -> Mb[k'][p][c]: reg pairs = consecutive c -> single b32 writes ----
    {
        const int rowpA = pA * 36 + (q << 2);
        const int a0 = l15 * 580 + rowpA;          // nt=0
        const int a1 = (16 + l15) * 580 + rowpA;   // nt=1
        *(u32*)&Mb_s[a0]      = pk16(DA00[0], DA00[1]);
        *(u32*)&Mb_s[a0 + 2]  = pk16(DA00[2], DA00[3]);
        *(u32*)&Mb_s[a0 + 16] = pk16(DA10[0], DA10[1]);
        *(u32*)&Mb_s[a0 + 18] = pk16(DA10[2], DA10[3]);
        *(u32*)&Mb_s[a1]      = pk16(DA01[0], DA01[1]);
        *(u32*)&Mb_s[a1 + 2]  = pk16(DA01[2], DA01[3]);
        *(u32*)&Mb_s[a1 + 16] = pk16(DA11[0], DA11[1]);
        *(u32*)&Mb_s[a1 + 18] = pk16(DA11[2], DA11[3]);
        const int rowpB = pB * 36 + (q << 2);
        const int c0 = l15 * 580 + rowpB;
        const int c1 = (16 + l15) * 580 + rowpB;
        *(u32*)&Mb_s[c0]      = pk16(DB00[0], DB00[1]);
        *(u32*)&Mb_s[c0 + 2]  = pk16(DB00[2], DB00[3]);
        *(u32*)&Mb_s[c0 + 16] = pk16(DB10[0], DB10[1]);
        *(u32*)&Mb_s[c0 + 18] = pk16(DB10[2], DB10[3]);
        *(u32*)&Mb_s[c1]      = pk16(DB01[0], DB01[1]);
        *(u32*)&Mb_s[c1 + 2]  = pk16(DB01[2], DB01[3]);
        *(u32*)&Mb_s[c1 + 16] = pk16(DB11[0], DB11[1]);
        *(u32*)&Mb_s[c1 + 18] = pk16(DB11[2], DB11[3]);
        if (l15 < 4) {   // nt=2: k' = 32..35
            const int a2 = (32 + l15) * 580 + rowpA;
            *(u32*)&Mb_s[a2]      = pk16(DA02[0], DA02[1]);
            *(u32*)&Mb_s[a2 + 2]  = pk16(DA02[2], DA02[3]);
            *(u32*)&Mb_s[a2 + 16] = pk16(DA12[0], DA12[1]);
            *(u32*)&Mb_s[a2 + 18] = pk16(DA12[2], DA12[3]);
            const int c2 = (32 + l15) * 580 + rowpB;
            *(u32*)&Mb_s[c2]      = pk16(DB02[0], DB02[1]);
            *(u32*)&Mb_s[c2 + 2]  = pk16(DB02[2], DB02[3]);
            *(u32*)&Mb_s[c2 + 16] = pk16(DB12[0], DB12[1]);
            *(u32*)&Mb_s[c2 + 18] = pk16(DB12[2], DB12[3]);
        }
    }
    __syncthreads();

    // ============ Phase 2: out(32d x 16p) = W . M via MFMA, 8 waves (dt x 9-kt seg) ============
    {
        const int dt  = w >> 2;       // 0,1
        const int seg = w & 3;        // 9 kt-steps each
        f32x4 acc2 = {0.0f, 0.0f, 0.0f, 0.0f};
        const int kt0 = seg * 9;
        #pragma unroll 3
        for (int kt = kt0; kt < kt0 + 9; ++kt) {
            const f16x8 af = *(const f16x8*)&Wfrag[((size_t)((kt * 2 + dt) * 64 + lane)) << 3];
            const int mbase = kt * 580 + l15 * 36 + (q << 3);
            const f16x4 mlo = *(const f16x4*)&Mb_s[mbase];
            const f16x4 mhi = *(const f16x4*)&Mb_s[mbase + 4];
            const f16x8 bf  = __builtin_shufflevector(mlo, mhi, 0, 1, 2, 3, 4, 5, 6, 7);
            acc2 = __builtin_amdgcn_mfma_f32_16x16x32_f16(af, bf, acc2, 0, 0, 0);
        }
        *(f32x4*)&Cp[(w * 64 + lane) * 4] = acc2;   // dedicated buffer: no barrier needed first
    }
    __syncthreads();

    if (w < 2) {
        const int dt2 = w;
        f32x4 s = *(const f32x4*)&Cp[((dt2 * 4 + 0) * 64 + lane) * 4];
        #pragma unroll
        for (int rphase = 1; rphase < 4; ++rphase) {
            const f32x4 t = *(const f32x4*)&Cp[((dt2 * 4 + rphase) * 64 + lane) * 4];
            s[0] += t[0]; s[1] += t[1]; s[2] += t[2]; s[3] += t[3];
        }
        const int drow = dt2 * 16 + (lane >> 4) * 4;   // D row = (lane>>4)*4 + reg
        const int col  = b0 + (lane & 15);
        #pragma unroll
        for (int rr = 0; rr < 4; ++rr) {
            out[(((n_ << 5) + drow + rr) << 13) + col] = s[rr];
        }
    }
}

extern "C" void kernel_launch(void* const* d_in, const int* in_sizes, int n_in,
                              void* d_out, int out_size, void* d_ws, size_t ws_size,
                              hipStream_t stream)
{
    const float* inp    = (const float*)d_in[0];
    const float* coords = (const float*)d_in[1];
    const float* rmask  = (const float*)d_in[2];
    const float* W      = (const float*)d_in[3];
    const int*   neigh  = (const int*)d_in[4];
    float*       outp   = (float*)d_out;

    float*          inp_t = (float*)d_ws;                                 // 4 MB
    unsigned short* Wfrag = (unsigned short*)((char*)d_ws + (4u << 20));  // 73.7 KB

    prep_kernel<<<1168, 256, 0, stream>>>(inp, W, inp_t, Wfrag);
    se3_main<<<2048, 512, 0, stream>>>(inp_t, coords, rmask, neigh, Wfrag, outp);
}